// Round 12
// baseline (136.191 us; speedup 1.0000x reference)
//
#include <hip/hip_runtime.h>
#include <float.h>

// loss = (1/(E(E-1))) * sum_{i,j: t_i != t_j} relu(pred[i,t_j] - (f_own[j]-1)) / (N[t_i] N[t_j])
// Identity: sum_{k<S} relu(p - thr_k) = S*p - sum_{k<S} min(p, thr_k) for any S >= cnt
// (FLT_MAX pads contribute exactly 0). Thread = class; thresholds in float4 registers;
// rows stream coalesced; zero inner-loop LDS; no same-address device atomics.
// Fast path capped at 24 slots (BODYQ(6)) to keep VGPR <= 56 -> full occupancy;
// counts 25..63 take the runtime-loop fallback (P ~ 0.1% of classes).
// 4 kernels: init (zero fill + FLT_MAX pre-pad), scatter, main (invN inline, per-block
// partial store), fin (diag + E + reduce, single block).

#define CCLS 1000
#define PADF 64     // float slots per class (fallback supports count <= 64)
#define TPB 256
#define CCH 250     // classes per chunk -> 4 chunks
#define NCH 4
#define NRBLK 512   // row blocks per chunk: RPB = 12288/512 = 24
#define NBLK (NCH * NRBLK)
#define RMAX 32

__global__ void k_init(int* fill, float4* thrP4) {
    int t = blockIdx.x * 256 + threadIdx.x;
    if (t < CCLS) fill[t] = 0;
    if (t < CCLS * 8) {   // pre-pad slots [0,32) of every class with FLT_MAX
        int c = t >> 3, q = t & 7;
        thrP4[c * (PADF / 4) + q] = make_float4(FLT_MAX, FLT_MAX, FLT_MAX, FLT_MAX);
    }
}

__global__ void k_scatter(const float* __restrict__ pred, const int* __restrict__ target,
                          int* fill, float* thrP, int B) {
    int j = blockIdx.x * 256 + threadIdx.x;
    if (j >= B) return;
    int tj = target[j];
    float fo = pred[(size_t)j * CCLS + tj];  // f_own[j]
    int pos = atomicAdd(&fill[tj], 1);       // scattered addresses, low contention
    if (pos < PADF) thrP[tj * PADF + pos] = fo - 1.0f;
}

// Fully-static body: NQ float4 threshold registers, 8-row batches, 32-bit offsets
// from the wave-uniform block base (compiler keeps base in SGPRs).
#define BODYQ(NQ)                                                                   \
    {                                                                               \
        float4 tq[NQ];                                                              \
        _Pragma("unroll") for (int q = 0; q < NQ; ++q) tq[q] = tp4[q];              \
        const float fS = (float)(4 * NQ);                                           \
        int r = 0;                                                                  \
        _Pragma("unroll 1") for (; r + 8 <= rows; r += 8) {                         \
            const int o = r * CCLS + c;                                             \
            const float p0 = pb[o];                                                 \
            const float p1 = pb[o + 1 * CCLS];                                      \
            const float p2 = pb[o + 2 * CCLS];                                      \
            const float p3 = pb[o + 3 * CCLS];                                      \
            const float p4 = pb[o + 4 * CCLS];                                      \
            const float p5 = pb[o + 5 * CCLS];                                      \
            const float p6 = pb[o + 6 * CCLS];                                      \
            const float p7 = pb[o + 7 * CCLS];                                      \
            float a0 = 0.f, a1 = 0.f, a2 = 0.f, a3 = 0.f;                           \
            float a4 = 0.f, a5 = 0.f, a6 = 0.f, a7 = 0.f;                           \
            _Pragma("unroll") for (int q = 0; q < NQ; ++q) {                        \
                a0 += (fminf(p0, tq[q].x) + fminf(p0, tq[q].y))                     \
                    + (fminf(p0, tq[q].z) + fminf(p0, tq[q].w));                    \
                a1 += (fminf(p1, tq[q].x) + fminf(p1, tq[q].y))                     \
                    + (fminf(p1, tq[q].z) + fminf(p1, tq[q].w));                    \
                a2 += (fminf(p2, tq[q].x) + fminf(p2, tq[q].y))                     \
                    + (fminf(p2, tq[q].z) + fminf(p2, tq[q].w));                    \
                a3 += (fminf(p3, tq[q].x) + fminf(p3, tq[q].y))                     \
                    + (fminf(p3, tq[q].z) + fminf(p3, tq[q].w));                    \
                a4 += (fminf(p4, tq[q].x) + fminf(p4, tq[q].y))                     \
                    + (fminf(p4, tq[q].z) + fminf(p4, tq[q].w));                    \
                a5 += (fminf(p5, tq[q].x) + fminf(p5, tq[q].y))                     \
                    + (fminf(p5, tq[q].z) + fminf(p5, tq[q].w));                    \
                a6 += (fminf(p6, tq[q].x) + fminf(p6, tq[q].y))                     \
                    + (fminf(p6, tq[q].z) + fminf(p6, tq[q].w));                    \
                a7 += (fminf(p7, tq[q].x) + fminf(p7, tq[q].y))                     \
                    + (fminf(p7, tq[q].z) + fminf(p7, tq[q].w));                    \
            }                                                                       \
            acc = fmaf(fmaf(fS, p0, -a0), rowW[r + 0], acc);                        \
            acc = fmaf(fmaf(fS, p1, -a1), rowW[r + 1], acc);                        \
            acc = fmaf(fmaf(fS, p2, -a2), rowW[r + 2], acc);                        \
            acc = fmaf(fmaf(fS, p3, -a3), rowW[r + 3], acc);                        \
            acc = fmaf(fmaf(fS, p4, -a4), rowW[r + 4], acc);                        \
            acc = fmaf(fmaf(fS, p5, -a5), rowW[r + 5], acc);                        \
            acc = fmaf(fmaf(fS, p6, -a6), rowW[r + 6], acc);                        \
            acc = fmaf(fmaf(fS, p7, -a7), rowW[r + 7], acc);                        \
        }                                                                           \
        for (; r < rows; ++r) {                                                     \
            const float p = pb[r * CCLS + c];                                       \
            float a = 0.f;                                                          \
            _Pragma("unroll") for (int q = 0; q < NQ; ++q) {                        \
                a += (fminf(p, tq[q].x) + fminf(p, tq[q].y))                        \
                   + (fminf(p, tq[q].z) + fminf(p, tq[q].w));                       \
            }                                                                       \
            acc = fmaf(fmaf(fS, p, -a), rowW[r], acc);                              \
        }                                                                           \
    }

__global__ __launch_bounds__(TPB) void k_main(const float* __restrict__ pred,
        const int* __restrict__ target, const float* __restrict__ thrP,
        const int* __restrict__ fill,
        float* __restrict__ part, int B, int RPB) {
    __shared__ float rowW[RMAX];
    __shared__ float redL[TPB / 64];

    const int tid = threadIdx.x;
    const int chunk = blockIdx.x / NRBLK;
    const int rblk = blockIdx.x % NRBLK;
    const int c0 = chunk * CCH;
    const int rbase = rblk * RPB;
    const int rows = min(min(RPB, B - rbase), RMAX);

    for (int r = tid; r < rows; r += TPB) {
        int t = target[rbase + r];
        rowW[r] = 1.0f / (float)fill[t];   // fill[t] >= 1 (t occurs in the batch)
    }
    __syncthreads();

    const int ccS = min(tid, CCH - 1);
    const int c = c0 + ccS;
    const int cntR = fill[c];
    const int cnt = min(cntR, PADF);
    const float invc = (tid < CCH && cntR > 0) ? 1.0f / (float)cntR : 0.f;

    int wmx = cnt;                       // wave-uniform max count
    for (int o = 32; o; o >>= 1) wmx = max(wmx, __shfl_xor(wmx, o));

    const float* pb = pred + (size_t)rbase * CCLS;   // wave-uniform base
    const float4* tp4 = (const float4*)(thrP + (size_t)c * PADF);
    float acc = 0.f;

    if (wmx <= 24) {
        const int nq = (wmx + 3) >> 2;   // 1..6, wave-uniform
        if (nq <= 2)      { BODYQ(2) }
        else if (nq <= 4) { BODYQ(4) }
        else              { BODYQ(6) }
    } else {
        // correctness fallback (some count in 25..64): per-lane runtime bound, L2-cached
        const float* tg = thrP + (size_t)c * PADF;
        for (int r = 0; r < rows; ++r) {
            const float p = pb[r * CCLS + c];
            float s = 0.f;
            for (int k = 0; k < cnt; ++k) s += fminf(p, tg[k]);
            acc = fmaf(fmaf((float)cnt, p, -s), rowW[r], acc);
        }
    }
    acc *= invc;

    for (int o = 32; o; o >>= 1) acc += __shfl_down(acc, o);
    if ((tid & 63) == 0) redL[tid >> 6] = acc;
    __syncthreads();
    if (tid == 0) {
        float ssum = 0.f;
#pragma unroll
        for (int k = 0; k < TPB / 64; ++k) ssum += redL[k];
        part[blockIdx.x] = ssum;          // plain store, no contention
    }
}

// Single-block epilogue: diagonal sum (two classes per wave, half-wave each),
// E count, partial-sum reduction, final output.
__global__ __launch_bounds__(1024) void k_fin(const float* __restrict__ part,
        const int* __restrict__ fill, const float* __restrict__ thrP,
        float* __restrict__ out) {
    __shared__ float wS[16], wD[16];
    __shared__ int wE[16];
    const int tid = threadIdx.x;
    const int wid = tid >> 6, lane = tid & 63;
    const int l2 = lane & 31;

    float dsum = 0.f;
    for (int cp = wid; cp < CCLS / 2; cp += 16) {
        const int cA = 2 * cp, cB = 2 * cp + 1;
        const int cntA = fill[cA], cntB = fill[cB];
        if (cntA <= 31 && cntB <= 31) {
            const int c = (lane >= 32) ? cB : cA;
            const int cnt = (lane >= 32) ? cntB : cntA;
            const float v = (l2 < cnt) ? thrP[(size_t)c * PADF + l2] : 0.f;
            const float vp1 = v + 1.0f;   // f_own of this element
            const int clmx = max(cntA, cntB);
            float F = 0.f;
            for (int k = 0; k < clmx; ++k) {
                const float u = __shfl(v, k + (lane & 32));  // broadcast within own half
                F += (k < cnt) ? fmaxf(vp1 - u, 0.f) : 0.f;
            }
            if (l2 < cnt && cnt > 0) {
                const float ic = 1.0f / (float)cnt;
                dsum += F * ic * ic;
            }
        } else if (lane == 0) {
            // rare (count > 31): exact serial O(cnt^2)
            for (int s = 0; s < 2; ++s) {
                const int c = s ? cB : cA;
                const int cnt = fill[c];
                const int cl = min(cnt, PADF);
                if (cnt > 0) {
                    float F = 0.f;
                    for (int i = 0; i < cl; ++i) {
                        const float fi = thrP[(size_t)c * PADF + i] + 1.0f;
                        for (int k = 0; k < cl; ++k)
                            F += fmaxf(fi - thrP[(size_t)c * PADF + k], 0.f);
                    }
                    const float ic = 1.0f / (float)cnt;
                    dsum += F * ic * ic;
                }
            }
        }
    }

    float psum = 0.f;
    for (int i = tid; i < NBLK; i += 1024) psum += part[i];
    int esum = 0;
    for (int c = tid; c < CCLS; c += 1024) esum += (fill[c] > 0) ? 1 : 0;

    for (int o = 32; o; o >>= 1) {
        dsum += __shfl_down(dsum, o);
        psum += __shfl_down(psum, o);
        esum += __shfl_down(esum, o);
    }
    if (lane == 0) { wS[wid] = psum; wD[wid] = dsum; wE[wid] = esum; }
    __syncthreads();
    if (tid == 0) {
        float tp = 0.f, td = 0.f;
        int te = 0;
#pragma unroll
        for (int k = 0; k < 16; ++k) { tp += wS[k]; td += wD[k]; te += wE[k]; }
        float E = (float)te;
        out[0] = (tp - td) / (E * (E - 1.0f));
    }
}

extern "C" void kernel_launch(void* const* d_in, const int* in_sizes, int n_in,
                              void* d_out, int out_size, void* d_ws, size_t ws_size,
                              hipStream_t stream) {
    const float* pred = (const float*)d_in[0];
    const int* target = (const int*)d_in[1];
    const int B = in_sizes[1];  // 12288

    char* ws = (char*)d_ws;
    int* fill   = (int*)(ws + 0);        // 1000 ints
    float* part = (float*)(ws + 4096);   // 2048 floats
    float* thrP = (float*)(ws + 16384);  // 1000*64 floats (256KB)

    const int gb = (B + 255) / 256;
    const int RPB = (B + NRBLK - 1) / NRBLK;

    k_init<<<32, 256, 0, stream>>>(fill, (float4*)thrP);
    k_scatter<<<gb, 256, 0, stream>>>(pred, target, fill, thrP, B);
    k_main<<<NBLK, TPB, 0, stream>>>(pred, target, thrP, fill, part, B, RPB);
    k_fin<<<1, 1024, 0, stream>>>(part, fill, thrP, (float*)d_out);
}

// Round 13
// 87.183 us; speedup vs baseline: 1.5621x; 1.5621x over previous
//
#include <hip/hip_runtime.h>
#include <float.h>

// loss = (1/(E(E-1))) * sum_{i,j: t_i != t_j} relu(pred[i,t_j] - (f_own[j]-1)) / (N[t_i] N[t_j])
// Identity: sum_{k<S} relu(p - thr_k) = S*p - sum_{k<S} min(p, thr_k) for any S >= cnt
// (FLT_MAX pads contribute exactly 0). Thread = class; thresholds in float4 registers;
// rows stream coalesced; zero inner-loop LDS; no same-address device atomics.
// Fast path gate wmx <= 32 (BODYQ up to 8 quads) -- R11's <=24 gate caused fallback
// stragglers on a real count in 25..32. Row batch = 4 to keep VGPR < 64 (occupancy step).

#define CCLS 1000
#define PADF 64     // float slots per class (fallback supports count <= 64)
#define TPB 256
#define CCH 250     // classes per chunk -> 4 chunks
#define NCH 4
#define NRBLK 512   // row blocks per chunk: RPB = 12288/512 = 24
#define NBLK (NCH * NRBLK)
#define RMAX 32

__global__ void k_init(int* fill, float4* thrP4) {
    int t = blockIdx.x * 256 + threadIdx.x;
    if (t < CCLS) fill[t] = 0;
    if (t < CCLS * 8) {   // pre-pad slots [0,32) of every class with FLT_MAX
        int c = t >> 3, q = t & 7;
        thrP4[c * (PADF / 4) + q] = make_float4(FLT_MAX, FLT_MAX, FLT_MAX, FLT_MAX);
    }
}

__global__ void k_scatter(const float* __restrict__ pred, const int* __restrict__ target,
                          int* fill, float* thrP, int B) {
    int j = blockIdx.x * 256 + threadIdx.x;
    if (j >= B) return;
    int tj = target[j];
    float fo = pred[(size_t)j * CCLS + tj];  // f_own[j]
    int pos = atomicAdd(&fill[tj], 1);       // scattered addresses, low contention
    if (pos < PADF) thrP[tj * PADF + pos] = fo - 1.0f;
}

// Fully-static body: NQ float4 threshold registers, 4-row batches (VGPR budget < 64).
#define BODYQ(NQ)                                                                   \
    {                                                                               \
        float4 tq[NQ];                                                              \
        _Pragma("unroll") for (int q = 0; q < NQ; ++q) tq[q] = tp4[q];              \
        const float fS = (float)(4 * NQ);                                           \
        int r = 0;                                                                  \
        _Pragma("unroll 1") for (; r + 4 <= rows; r += 4) {                         \
            const float p0 = pp[(size_t)(r + 0) * CCLS];                            \
            const float p1 = pp[(size_t)(r + 1) * CCLS];                            \
            const float p2 = pp[(size_t)(r + 2) * CCLS];                            \
            const float p3 = pp[(size_t)(r + 3) * CCLS];                            \
            float a0 = 0.f, a1 = 0.f, a2 = 0.f, a3 = 0.f;                           \
            _Pragma("unroll") for (int q = 0; q < NQ; ++q) {                        \
                a0 += (fminf(p0, tq[q].x) + fminf(p0, tq[q].y))                     \
                    + (fminf(p0, tq[q].z) + fminf(p0, tq[q].w));                    \
                a1 += (fminf(p1, tq[q].x) + fminf(p1, tq[q].y))                     \
                    + (fminf(p1, tq[q].z) + fminf(p1, tq[q].w));                    \
                a2 += (fminf(p2, tq[q].x) + fminf(p2, tq[q].y))                     \
                    + (fminf(p2, tq[q].z) + fminf(p2, tq[q].w));                    \
                a3 += (fminf(p3, tq[q].x) + fminf(p3, tq[q].y))                     \
                    + (fminf(p3, tq[q].z) + fminf(p3, tq[q].w));                    \
            }                                                                       \
            acc = fmaf(fmaf(fS, p0, -a0), rowW[r + 0], acc);                        \
            acc = fmaf(fmaf(fS, p1, -a1), rowW[r + 1], acc);                        \
            acc = fmaf(fmaf(fS, p2, -a2), rowW[r + 2], acc);                        \
            acc = fmaf(fmaf(fS, p3, -a3), rowW[r + 3], acc);                        \
        }                                                                           \
        for (; r < rows; ++r) {                                                     \
            const float p = pp[(size_t)r * CCLS];                                   \
            float a = 0.f;                                                          \
            _Pragma("unroll") for (int q = 0; q < NQ; ++q) {                        \
                a += (fminf(p, tq[q].x) + fminf(p, tq[q].y))                        \
                   + (fminf(p, tq[q].z) + fminf(p, tq[q].w));                       \
            }                                                                       \
            acc = fmaf(fmaf(fS, p, -a), rowW[r], acc);                              \
        }                                                                           \
    }

__global__ __launch_bounds__(TPB) void k_main(const float* __restrict__ pred,
        const int* __restrict__ target, const float* __restrict__ thrP,
        const int* __restrict__ fill,
        float* __restrict__ part, int B, int RPB) {
    __shared__ float rowW[RMAX];
    __shared__ float redL[TPB / 64];

    const int tid = threadIdx.x;
    const int chunk = blockIdx.x / NRBLK;
    const int rblk = blockIdx.x % NRBLK;
    const int c0 = chunk * CCH;
    const int rbase = rblk * RPB;
    const int rows = min(min(RPB, B - rbase), RMAX);

    for (int r = tid; r < rows; r += TPB) {
        int t = target[rbase + r];
        rowW[r] = 1.0f / (float)fill[t];   // fill[t] >= 1 (t occurs in the batch)
    }
    __syncthreads();

    const int ccS = min(tid, CCH - 1);
    const int c = c0 + ccS;
    const int cntR = fill[c];
    const int cnt = min(cntR, PADF);
    const float invc = (tid < CCH && cntR > 0) ? 1.0f / (float)cntR : 0.f;

    int wmx = cnt;                       // wave-uniform max count
    for (int o = 32; o; o >>= 1) wmx = max(wmx, __shfl_xor(wmx, o));

    const float4* tp4 = (const float4*)(thrP + (size_t)c * PADF);
    const float* pp = pred + (size_t)rbase * CCLS + c;
    float acc = 0.f;

    if (wmx <= 32) {
        const int nq = (wmx + 3) >> 2;   // 1..8, wave-uniform
        switch ((nq + 1) >> 1) {         // 2/4/6/8 quads
            case 0:
            case 1: BODYQ(2) break;
            case 2: BODYQ(4) break;
            case 3: BODYQ(6) break;
            default: BODYQ(8) break;
        }
    } else {
        // correctness fallback (some count in 33..64): per-lane runtime bound, L2-cached
        const float* tg = thrP + (size_t)c * PADF;
        for (int r = 0; r < rows; ++r) {
            const float p = pp[(size_t)r * CCLS];
            float s = 0.f;
            for (int k = 0; k < cnt; ++k) s += fminf(p, tg[k]);
            acc = fmaf(fmaf((float)cnt, p, -s), rowW[r], acc);
        }
    }
    acc *= invc;

    for (int o = 32; o; o >>= 1) acc += __shfl_down(acc, o);
    if ((tid & 63) == 0) redL[tid >> 6] = acc;
    __syncthreads();
    if (tid == 0) {
        float ssum = 0.f;
#pragma unroll
        for (int k = 0; k < TPB / 64; ++k) ssum += redL[k];
        part[blockIdx.x] = ssum;          // plain store, no contention
    }
}

// Single-block epilogue: diagonal sum (two classes per wave, half-wave each),
// E count, partial-sum reduction, final output.
__global__ __launch_bounds__(1024) void k_fin(const float* __restrict__ part,
        const int* __restrict__ fill, const float* __restrict__ thrP,
        float* __restrict__ out) {
    __shared__ float wS[16], wD[16];
    __shared__ int wE[16];
    const int tid = threadIdx.x;
    const int wid = tid >> 6, lane = tid & 63;
    const int l2 = lane & 31;

    float dsum = 0.f;
    for (int cp = wid; cp < CCLS / 2; cp += 16) {
        const int cA = 2 * cp, cB = 2 * cp + 1;
        const int cntA = fill[cA], cntB = fill[cB];
        if (cntA <= 31 && cntB <= 31) {
            const int c = (lane >= 32) ? cB : cA;
            const int cnt = (lane >= 32) ? cntB : cntA;
            const float v = (l2 < cnt) ? thrP[(size_t)c * PADF + l2] : 0.f;
            const float vp1 = v + 1.0f;   // f_own of this element
            const int clmx = max(cntA, cntB);
            float F = 0.f;
            for (int k = 0; k < clmx; ++k) {
                const float u = __shfl(v, k + (lane & 32));  // broadcast within own half
                F += (k < cnt) ? fmaxf(vp1 - u, 0.f) : 0.f;
            }
            if (l2 < cnt && cnt > 0) {
                const float ic = 1.0f / (float)cnt;
                dsum += F * ic * ic;
            }
        } else if (lane == 0) {
            // rare (count > 31): exact serial O(cnt^2)
            for (int s = 0; s < 2; ++s) {
                const int c = s ? cB : cA;
                const int cnt = fill[c];
                const int cl = min(cnt, PADF);
                if (cnt > 0) {
                    float F = 0.f;
                    for (int i = 0; i < cl; ++i) {
                        const float fi = thrP[(size_t)c * PADF + i] + 1.0f;
                        for (int k = 0; k < cl; ++k)
                            F += fmaxf(fi - thrP[(size_t)c * PADF + k], 0.f);
                    }
                    const float ic = 1.0f / (float)cnt;
                    dsum += F * ic * ic;
                }
            }
        }
    }

    float psum = 0.f;
    for (int i = tid; i < NBLK; i += 1024) psum += part[i];
    int esum = 0;
    for (int c = tid; c < CCLS; c += 1024) esum += (fill[c] > 0) ? 1 : 0;

    for (int o = 32; o; o >>= 1) {
        dsum += __shfl_down(dsum, o);
        psum += __shfl_down(psum, o);
        esum += __shfl_down(esum, o);
    }
    if (lane == 0) { wS[wid] = psum; wD[wid] = dsum; wE[wid] = esum; }
    __syncthreads();
    if (tid == 0) {
        float tp = 0.f, td = 0.f;
        int te = 0;
#pragma unroll
        for (int k = 0; k < 16; ++k) { tp += wS[k]; td += wD[k]; te += wE[k]; }
        float E = (float)te;
        out[0] = (tp - td) / (E * (E - 1.0f));
    }
}

extern "C" void kernel_launch(void* const* d_in, const int* in_sizes, int n_in,
                              void* d_out, int out_size, void* d_ws, size_t ws_size,
                              hipStream_t stream) {
    const float* pred = (const float*)d_in[0];
    const int* target = (const int*)d_in[1];
    const int B = in_sizes[1];  // 12288

    char* ws = (char*)d_ws;
    int* fill   = (int*)(ws + 0);        // 1000 ints
    float* part = (float*)(ws + 4096);   // 2048 floats
    float* thrP = (float*)(ws + 16384);  // 1000*64 floats (256KB)

    const int gb = (B + 255) / 256;
    const int RPB = (B + NRBLK - 1) / NRBLK;

    k_init<<<32, 256, 0, stream>>>(fill, (float4*)thrP);
    k_scatter<<<gb, 256, 0, stream>>>(pred, target, fill, thrP, B);
    k_main<<<NBLK, TPB, 0, stream>>>(pred, target, thrP, fill, part, B, RPB);
    k_fin<<<1, 1024, 0, stream>>>(part, fill, thrP, (float*)d_out);
}

// Round 14
// 44.160 us; speedup vs baseline: 3.0840x; 1.9743x over previous
//
#include <hip/hip_runtime.h>
#include <float.h>

// loss = (1/(E(E-1))) * sum_{i,j: t_i != t_j} relu(pred[i,t_j] - (f_own[j]-1)) / (N[t_i] N[t_j])
// Identity: sum_{k<S} relu(p - thr_k) = S*p - sum_{k<S} min(p, thr_k) for any S >= cnt
// (FLT_MAX pads contribute exactly 0). Thread = class; thresholds in float4 registers;
// rows stream coalesced; zero inner-loop LDS; no same-address device atomics.
// Diagonal computed by multi-block k_diag (wave per class, plain stores) -- NOT in the
// single-block epilogue (R12's fused k_fin serialized it: 54 us). k_final is streaming-only.

#define CCLS 1000
#define PADF 64     // float slots per class (fallback supports count <= 64)
#define TPB 256
#define CCH 250     // classes per chunk -> 4 chunks
#define NCH 4
#define NRBLK 512   // row blocks per chunk: RPB = 12288/512 = 24
#define NBLK (NCH * NRBLK)
#define RMAX 32

__global__ void k_init(int* fill, float4* thrP4) {
    int t = blockIdx.x * 256 + threadIdx.x;
    if (t < CCLS) fill[t] = 0;
    if (t < CCLS * 8) {   // pre-pad slots [0,32) of every class with FLT_MAX
        int c = t >> 3, q = t & 7;
        thrP4[c * (PADF / 4) + q] = make_float4(FLT_MAX, FLT_MAX, FLT_MAX, FLT_MAX);
    }
}

__global__ void k_scatter(const float* __restrict__ pred, const int* __restrict__ target,
                          int* fill, float* thrP, int B) {
    int j = blockIdx.x * 256 + threadIdx.x;
    if (j >= B) return;
    int tj = target[j];
    float fo = pred[(size_t)j * CCLS + tj];  // f_own[j]
    int pos = atomicAdd(&fill[tj], 1);       // scattered addresses, low contention
    if (pos < PADF) thrP[tj * PADF + pos] = fo - 1.0f;
}

// wave per class: diagArr[c] = sum_{i:t_i=c} F_c(f_own_i) / N_c^2, F_c(x)=sum_k relu(x-thr_k).
// 64-lane shfl handles any cnt <= 64 directly; plain stores only.
__global__ __launch_bounds__(256) void k_diag(const int* __restrict__ fill,
                                              const float* __restrict__ thrP,
                                              float* __restrict__ diagArr) {
    int c = (blockIdx.x * 256 + threadIdx.x) >> 6;
    int lane = threadIdx.x & 63;
    if (c >= CCLS) return;
    int cnt = fill[c];
    int cl = min(cnt, PADF);
    float v = (lane < cl) ? thrP[(size_t)c * PADF + lane] : 0.f;
    float vp1 = v + 1.0f;            // f_own of this element
    float F = 0.f;
    for (int k = 0; k < cl; ++k) {
        float u = __shfl(v, k);
        F += fmaxf(vp1 - u, 0.f);
    }
    if (lane >= cl) F = 0.f;
    for (int o = 32; o; o >>= 1) F += __shfl_down(F, o);
    if (lane == 0) {
        if (cnt > 0) {
            float ic = 1.0f / (float)cnt;
            diagArr[c] = F * ic * ic;
        } else {
            diagArr[c] = 0.f;
        }
    }
}

// Fully-static body: NQ float4 threshold registers, 4-row batches (VGPR budget < 64).
#define BODYQ(NQ)                                                                   \
    {                                                                               \
        float4 tq[NQ];                                                              \
        _Pragma("unroll") for (int q = 0; q < NQ; ++q) tq[q] = tp4[q];              \
        const float fS = (float)(4 * NQ);                                           \
        int r = 0;                                                                  \
        _Pragma("unroll 1") for (; r + 4 <= rows; r += 4) {                         \
            const float p0 = pp[(size_t)(r + 0) * CCLS];                            \
            const float p1 = pp[(size_t)(r + 1) * CCLS];                            \
            const float p2 = pp[(size_t)(r + 2) * CCLS];                            \
            const float p3 = pp[(size_t)(r + 3) * CCLS];                            \
            float a0 = 0.f, a1 = 0.f, a2 = 0.f, a3 = 0.f;                           \
            _Pragma("unroll") for (int q = 0; q < NQ; ++q) {                        \
                a0 += (fminf(p0, tq[q].x) + fminf(p0, tq[q].y))                     \
                    + (fminf(p0, tq[q].z) + fminf(p0, tq[q].w));                    \
                a1 += (fminf(p1, tq[q].x) + fminf(p1, tq[q].y))                     \
                    + (fminf(p1, tq[q].z) + fminf(p1, tq[q].w));                    \
                a2 += (fminf(p2, tq[q].x) + fminf(p2, tq[q].y))                     \
                    + (fminf(p2, tq[q].z) + fminf(p2, tq[q].w));                    \
                a3 += (fminf(p3, tq[q].x) + fminf(p3, tq[q].y))                     \
                    + (fminf(p3, tq[q].z) + fminf(p3, tq[q].w));                    \
            }                                                                       \
            acc = fmaf(fmaf(fS, p0, -a0), rowW[r + 0], acc);                        \
            acc = fmaf(fmaf(fS, p1, -a1), rowW[r + 1], acc);                        \
            acc = fmaf(fmaf(fS, p2, -a2), rowW[r + 2], acc);                        \
            acc = fmaf(fmaf(fS, p3, -a3), rowW[r + 3], acc);                        \
        }                                                                           \
        for (; r < rows; ++r) {                                                     \
            const float p = pp[(size_t)r * CCLS];                                   \
            float a = 0.f;                                                          \
            _Pragma("unroll") for (int q = 0; q < NQ; ++q) {                        \
                a += (fminf(p, tq[q].x) + fminf(p, tq[q].y))                        \
                   + (fminf(p, tq[q].z) + fminf(p, tq[q].w));                       \
            }                                                                       \
            acc = fmaf(fmaf(fS, p, -a), rowW[r], acc);                              \
        }                                                                           \
    }

__global__ __launch_bounds__(TPB) void k_main(const float* __restrict__ pred,
        const int* __restrict__ target, const float* __restrict__ thrP,
        const int* __restrict__ fill,
        float* __restrict__ part, int B, int RPB) {
    __shared__ float rowW[RMAX];
    __shared__ float redL[TPB / 64];

    const int tid = threadIdx.x;
    const int chunk = blockIdx.x / NRBLK;
    const int rblk = blockIdx.x % NRBLK;
    const int c0 = chunk * CCH;
    const int rbase = rblk * RPB;
    const int rows = min(min(RPB, B - rbase), RMAX);

    for (int r = tid; r < rows; r += TPB) {
        int t = target[rbase + r];
        rowW[r] = 1.0f / (float)fill[t];   // fill[t] >= 1 (t occurs in the batch)
    }
    __syncthreads();

    const int ccS = min(tid, CCH - 1);
    const int c = c0 + ccS;
    const int cntR = fill[c];
    const int cnt = min(cntR, PADF);
    const float invc = (tid < CCH && cntR > 0) ? 1.0f / (float)cntR : 0.f;

    int wmx = cnt;                       // wave-uniform max count
    for (int o = 32; o; o >>= 1) wmx = max(wmx, __shfl_xor(wmx, o));

    const float4* tp4 = (const float4*)(thrP + (size_t)c * PADF);
    const float* pp = pred + (size_t)rbase * CCLS + c;
    float acc = 0.f;

    if (wmx <= 32) {
        const int nq = (wmx + 3) >> 2;   // 1..8, wave-uniform
        switch ((nq + 1) >> 1) {         // 2/4/6/8 quads
            case 0:
            case 1: BODYQ(2) break;
            case 2: BODYQ(4) break;
            case 3: BODYQ(6) break;
            default: BODYQ(8) break;
        }
    } else {
        // correctness fallback (some count in 33..64): per-lane runtime bound, L2-cached
        const float* tg = thrP + (size_t)c * PADF;
        for (int r = 0; r < rows; ++r) {
            const float p = pp[(size_t)r * CCLS];
            float s = 0.f;
            for (int k = 0; k < cnt; ++k) s += fminf(p, tg[k]);
            acc = fmaf(fmaf((float)cnt, p, -s), rowW[r], acc);
        }
    }
    acc *= invc;

    for (int o = 32; o; o >>= 1) acc += __shfl_down(acc, o);
    if ((tid & 63) == 0) redL[tid >> 6] = acc;
    __syncthreads();
    if (tid == 0) {
        float ssum = 0.f;
#pragma unroll
        for (int k = 0; k < TPB / 64; ++k) ssum += redL[k];
        part[blockIdx.x] = ssum;          // plain store, no contention
    }
}

// Single-block streaming epilogue: reduce partials + diag + E. No dependent chains.
__global__ __launch_bounds__(1024) void k_final(const float* __restrict__ part,
        const int* __restrict__ fill, const float* __restrict__ diagArr,
        float* __restrict__ out) {
    __shared__ float wP[16], wD[16];
    __shared__ int wE[16];
    const int tid = threadIdx.x;
    float sp = 0.f;
    for (int i = tid; i < NBLK; i += 1024) sp += part[i];
    float sd = 0.f;
    int se = 0;
    for (int c = tid; c < CCLS; c += 1024) {
        sd += diagArr[c];
        se += (fill[c] > 0) ? 1 : 0;
    }
    for (int o = 32; o; o >>= 1) {
        sp += __shfl_down(sp, o);
        sd += __shfl_down(sd, o);
        se += __shfl_down(se, o);
    }
    if ((tid & 63) == 0) { wP[tid >> 6] = sp; wD[tid >> 6] = sd; wE[tid >> 6] = se; }
    __syncthreads();
    if (tid == 0) {
        float tp = 0.f, td = 0.f;
        int te = 0;
#pragma unroll
        for (int k = 0; k < 16; ++k) { tp += wP[k]; td += wD[k]; te += wE[k]; }
        float E = (float)te;
        out[0] = (tp - td) / (E * (E - 1.0f));
    }
}

extern "C" void kernel_launch(void* const* d_in, const int* in_sizes, int n_in,
                              void* d_out, int out_size, void* d_ws, size_t ws_size,
                              hipStream_t stream) {
    const float* pred = (const float*)d_in[0];
    const int* target = (const int*)d_in[1];
    const int B = in_sizes[1];  // 12288

    char* ws = (char*)d_ws;
    int* fill     = (int*)(ws + 0);        // 1000 ints
    float* part   = (float*)(ws + 4096);   // 2048 floats
    float* diagAr = (float*)(ws + 12352);  // 1000 floats
    float* thrP   = (float*)(ws + 16384);  // 1000*64 floats (256KB)

    const int gb = (B + 255) / 256;
    const int RPB = (B + NRBLK - 1) / NRBLK;

    k_init<<<32, 256, 0, stream>>>(fill, (float4*)thrP);
    k_scatter<<<gb, 256, 0, stream>>>(pred, target, fill, thrP, B);
    k_diag<<<(CCLS * 64 + 255) / 256, 256, 0, stream>>>(fill, thrP, diagAr);
    k_main<<<NBLK, TPB, 0, stream>>>(pred, target, thrP, fill, part, B, RPB);
    k_final<<<1, 1024, 0, stream>>>(part, fill, diagAr, (float*)d_out);
}

// Round 15
// 40.882 us; speedup vs baseline: 3.3313x; 1.0802x over previous
//
#include <hip/hip_runtime.h>
#include <float.h>

// loss = (1/(E(E-1))) * sum_{i,j: t_i != t_j} relu(pred[i,t_j] - (f_own[j]-1)) / (N[t_i] N[t_j])
// Identity: sum_{k<S} relu(p - thr_k) = S*p - sum_{k<S} min(p, thr_k) for any S >= cnt
// (FLT_MAX pads contribute exactly 0). Thread = class; thresholds in float4 registers;
// rows stream coalesced; zero inner-loop LDS; no same-address device atomics.
// Diagonal (c == t_i) excluded IN-LOOP (2 VALU/item) -- cheaper than R13's separate
// k_diag kernel (launch + boundary ~5 us). 4 kernels: init, scatter, main, final.

#define CCLS 1000
#define PADF 64     // float slots per class (fallback supports count <= 64)
#define TPB 256
#define CCH 250     // classes per chunk -> 4 chunks
#define NCH 4
#define NRBLK 512   // row blocks per chunk: RPB = 12288/512 = 24
#define NBLK (NCH * NRBLK)
#define RMAX 32

__global__ void k_init(int* fill, float4* thrP4) {
    int t = blockIdx.x * 256 + threadIdx.x;
    if (t < CCLS) fill[t] = 0;
    if (t < CCLS * 8) {   // pre-pad slots [0,32) of every class with FLT_MAX
        int c = t >> 3, q = t & 7;
        thrP4[c * (PADF / 4) + q] = make_float4(FLT_MAX, FLT_MAX, FLT_MAX, FLT_MAX);
    }
}

__global__ void k_scatter(const float* __restrict__ pred, const int* __restrict__ target,
                          int* fill, float* thrP, int B) {
    int j = blockIdx.x * 256 + threadIdx.x;
    if (j >= B) return;
    int tj = target[j];
    float fo = pred[(size_t)j * CCLS + tj];  // f_own[j]
    int pos = atomicAdd(&fill[tj], 1);       // scattered addresses, low contention
    if (pos < PADF) thrP[tj * PADF + pos] = fo - 1.0f;
}

// Fully-static body: NQ float4 threshold registers, 4-row batches (VGPR < 64).
// Per row: wt = rowWT[r] = (target_as_float, invN[target]); exclude c == target in-loop.
#define BODYQ(NQ)                                                                   \
    {                                                                               \
        float4 tq[NQ];                                                              \
        _Pragma("unroll") for (int q = 0; q < NQ; ++q) tq[q] = tp4[q];              \
        const float fS = (float)(4 * NQ);                                           \
        int r = 0;                                                                  \
        _Pragma("unroll 1") for (; r + 4 <= rows; r += 4) {                         \
            const float p0 = pp[(size_t)(r + 0) * CCLS];                            \
            const float p1 = pp[(size_t)(r + 1) * CCLS];                            \
            const float p2 = pp[(size_t)(r + 2) * CCLS];                            \
            const float p3 = pp[(size_t)(r + 3) * CCLS];                            \
            float a0 = 0.f, a1 = 0.f, a2 = 0.f, a3 = 0.f;                           \
            _Pragma("unroll") for (int q = 0; q < NQ; ++q) {                        \
                a0 += (fminf(p0, tq[q].x) + fminf(p0, tq[q].y))                     \
                    + (fminf(p0, tq[q].z) + fminf(p0, tq[q].w));                    \
                a1 += (fminf(p1, tq[q].x) + fminf(p1, tq[q].y))                     \
                    + (fminf(p1, tq[q].z) + fminf(p1, tq[q].w));                    \
                a2 += (fminf(p2, tq[q].x) + fminf(p2, tq[q].y))                     \
                    + (fminf(p2, tq[q].z) + fminf(p2, tq[q].w));                    \
                a3 += (fminf(p3, tq[q].x) + fminf(p3, tq[q].y))                     \
                    + (fminf(p3, tq[q].z) + fminf(p3, tq[q].w));                    \
            }                                                                       \
            const float2 w0 = rowWT[r + 0], w1 = rowWT[r + 1];                      \
            const float2 w2 = rowWT[r + 2], w3 = rowWT[r + 3];                      \
            const float s0 = (c != __float_as_int(w0.x)) ? w0.y : 0.f;              \
            const float s1 = (c != __float_as_int(w1.x)) ? w1.y : 0.f;              \
            const float s2 = (c != __float_as_int(w2.x)) ? w2.y : 0.f;              \
            const float s3 = (c != __float_as_int(w3.x)) ? w3.y : 0.f;              \
            acc = fmaf(fmaf(fS, p0, -a0), s0, acc);                                 \
            acc = fmaf(fmaf(fS, p1, -a1), s1, acc);                                 \
            acc = fmaf(fmaf(fS, p2, -a2), s2, acc);                                 \
            acc = fmaf(fmaf(fS, p3, -a3), s3, acc);                                 \
        }                                                                           \
        for (; r < rows; ++r) {                                                     \
            const float p = pp[(size_t)r * CCLS];                                   \
            float a = 0.f;                                                          \
            _Pragma("unroll") for (int q = 0; q < NQ; ++q) {                        \
                a += (fminf(p, tq[q].x) + fminf(p, tq[q].y))                        \
                   + (fminf(p, tq[q].z) + fminf(p, tq[q].w));                       \
            }                                                                       \
            const float2 w = rowWT[r];                                              \
            const float s = (c != __float_as_int(w.x)) ? w.y : 0.f;                 \
            acc = fmaf(fmaf(fS, p, -a), s, acc);                                    \
        }                                                                           \
    }

__global__ __launch_bounds__(TPB) void k_main(const float* __restrict__ pred,
        const int* __restrict__ target, const float* __restrict__ thrP,
        const int* __restrict__ fill,
        float* __restrict__ part, int B, int RPB) {
    __shared__ float2 rowWT[RMAX];   // (target_as_float, invN[target]) per row
    __shared__ float redL[TPB / 64];

    const int tid = threadIdx.x;
    const int chunk = blockIdx.x / NRBLK;
    const int rblk = blockIdx.x % NRBLK;
    const int c0 = chunk * CCH;
    const int rbase = rblk * RPB;
    const int rows = min(min(RPB, B - rbase), RMAX);

    for (int r = tid; r < rows; r += TPB) {
        int t = target[rbase + r];
        rowWT[r] = make_float2(__int_as_float(t), 1.0f / (float)fill[t]);
    }
    __syncthreads();

    const int ccS = min(tid, CCH - 1);
    const int c = c0 + ccS;
    const int cntR = fill[c];
    const int cnt = min(cntR, PADF);
    const float invc = (tid < CCH && cntR > 0) ? 1.0f / (float)cntR : 0.f;

    int wmx = cnt;                       // wave-uniform max count
    for (int o = 32; o; o >>= 1) wmx = max(wmx, __shfl_xor(wmx, o));

    const float4* tp4 = (const float4*)(thrP + (size_t)c * PADF);
    const float* pp = pred + (size_t)rbase * CCLS + c;
    float acc = 0.f;

    if (wmx <= 32) {
        const int nq = (wmx + 3) >> 2;   // 1..8, wave-uniform
        switch ((nq + 1) >> 1) {         // 2/4/6/8 quads
            case 0:
            case 1: BODYQ(2) break;
            case 2: BODYQ(4) break;
            case 3: BODYQ(6) break;
            default: BODYQ(8) break;
        }
    } else {
        // correctness fallback (some count in 33..64): per-lane runtime bound, L2-cached
        const float* tg = thrP + (size_t)c * PADF;
        for (int r = 0; r < rows; ++r) {
            const float p = pp[(size_t)r * CCLS];
            float s = 0.f;
            for (int k = 0; k < cnt; ++k) s += fminf(p, tg[k]);
            const float2 w = rowWT[r];
            const float ws = (c != __float_as_int(w.x)) ? w.y : 0.f;
            acc = fmaf(fmaf((float)cnt, p, -s), ws, acc);
        }
    }
    acc *= invc;

    for (int o = 32; o; o >>= 1) acc += __shfl_down(acc, o);
    if ((tid & 63) == 0) redL[tid >> 6] = acc;
    __syncthreads();
    if (tid == 0) {
        float ssum = 0.f;
#pragma unroll
        for (int k = 0; k < TPB / 64; ++k) ssum += redL[k];
        part[blockIdx.x] = ssum;          // plain store, no contention
    }
}

// Single-block streaming epilogue: reduce partials + E count. No dependent chains.
__global__ __launch_bounds__(1024) void k_final(const float* __restrict__ part,
        const int* __restrict__ fill, float* __restrict__ out) {
    __shared__ float wP[16];
    __shared__ int wE[16];
    const int tid = threadIdx.x;
    float sp = 0.f;
    for (int i = tid; i < NBLK; i += 1024) sp += part[i];
    int se = 0;
    for (int c = tid; c < CCLS; c += 1024) se += (fill[c] > 0) ? 1 : 0;
    for (int o = 32; o; o >>= 1) {
        sp += __shfl_down(sp, o);
        se += __shfl_down(se, o);
    }
    if ((tid & 63) == 0) { wP[tid >> 6] = sp; wE[tid >> 6] = se; }
    __syncthreads();
    if (tid == 0) {
        float tp = 0.f;
        int te = 0;
#pragma unroll
        for (int k = 0; k < 16; ++k) { tp += wP[k]; te += wE[k]; }
        float E = (float)te;
        out[0] = tp / (E * (E - 1.0f));
    }
}

extern "C" void kernel_launch(void* const* d_in, const int* in_sizes, int n_in,
                              void* d_out, int out_size, void* d_ws, size_t ws_size,
                              hipStream_t stream) {
    const float* pred = (const float*)d_in[0];
    const int* target = (const int*)d_in[1];
    const int B = in_sizes[1];  // 12288

    char* ws = (char*)d_ws;
    int* fill   = (int*)(ws + 0);        // 1000 ints
    float* part = (float*)(ws + 4096);   // 2048 floats
    float* thrP = (float*)(ws + 16384);  // 1000*64 floats (256KB)

    const int gb = (B + 255) / 256;
    const int RPB = (B + NRBLK - 1) / NRBLK;

    k_init<<<32, 256, 0, stream>>>(fill, (float4*)thrP);
    k_scatter<<<gb, 256, 0, stream>>>(pred, target, fill, thrP, B);
    k_main<<<NBLK, TPB, 0, stream>>>(pred, target, thrP, fill, part, B, RPB);
    k_final<<<1, 1024, 0, stream>>>(part, fill, (float*)d_out);
}